// Round 5
// baseline (622.574 us; speedup 1.0000x reference)
//
#include <hip/hip_runtime.h>
#include <hip/hip_bf16.h>
#include <math.h>

#define DIM   1024
#define NEXP  8
#define HID   1536
#define NTOK  8192
#define NPOS  16384   // NTOK * TOP_K
#define PADR  128     // padding rows for tile overrun reads

typedef __attribute__((ext_vector_type(8))) short bf16x8;
typedef __attribute__((ext_vector_type(4))) float floatx4;

__device__ __forceinline__ unsigned short f2bf(float f) {
  unsigned int u = __float_as_uint(f);
  u += 0x7FFFu + ((u >> 16) & 1u);   // round-to-nearest-even
  return (unsigned short)(u >> 16);
}

__device__ __forceinline__ float bf2f(unsigned short h) {
  return __uint_as_float((unsigned int)h << 16);
}

__device__ __forceinline__ void async_cp16(void* lds, const void* g) {
  __builtin_amdgcn_global_load_lds(
      (const __attribute__((address_space(1))) unsigned int*)g,
      (__attribute__((address_space(3))) unsigned int*)lds, 16, 0, 0);
}

// count + exclusive-prefix offset for expert e, from hdr[0..7]
__device__ __forceinline__ int2 cnt_off(const int* __restrict__ hdr, int e) {
  int s = 0, c = 0;
#pragma unroll
  for (int i = 0; i < NEXP; ++i) {
    const int v = hdr[i];
    if (i < e) s += v;
    if (i == e) c = v;
  }
  return make_int2(c, s);
}

// ---------------- router: logits, top-2, softmax (no atomics) --------------
__global__ __launch_bounds__(256) void moe_router(
    const float* __restrict__ x, const float* __restrict__ Wr,
    int* __restrict__ meta_e, float* __restrict__ meta_w) {
  const int wave = threadIdx.x >> 6, lane = threadIdx.x & 63;
  const int token = blockIdx.x * 4 + wave;
  const float* xr = x + (size_t)token * DIM;
  float acc[NEXP];
#pragma unroll
  for (int e = 0; e < NEXP; ++e) acc[e] = 0.f;
  for (int i = lane; i < DIM; i += 64) {
    const float xv = xr[i];
    const float* wr = Wr + (size_t)i * NEXP;
#pragma unroll
    for (int e = 0; e < NEXP; ++e) acc[e] += xv * wr[e];
  }
#pragma unroll
  for (int off = 32; off > 0; off >>= 1) {
#pragma unroll
    for (int e = 0; e < NEXP; ++e) acc[e] += __shfl_down(acc[e], off);
  }
  if (lane == 0) {
    int i0 = 0; float v0 = acc[0];
#pragma unroll
    for (int e = 1; e < NEXP; ++e) if (acc[e] > v0) { v0 = acc[e]; i0 = e; }
    int i1 = -1; float v1 = -3.4e38f;
#pragma unroll
    for (int e = 0; e < NEXP; ++e) if (e != i0 && acc[e] > v1) { v1 = acc[e]; i1 = e; }
    const float w0 = 1.f / (1.f + expf(v1 - v0));  // stable softmax over top-2
    meta_e[token * 2 + 0] = i0;
    meta_e[token * 2 + 1] = i1;
    meta_w[token * 2 + 0] = w0;
    meta_w[token * 2 + 1] = 1.f - w0;
  }
}

// ------------- histogram: wave-aggregated counts into hdr[0..7] ------------
__global__ __launch_bounds__(256) void moe_hist(
    const int* __restrict__ meta_e, int* __restrict__ hdr) {
  const int idx = blockIdx.x * 256 + threadIdx.x;  // over NPOS entries
  const int lane = threadIdx.x & 63;
  const int e = meta_e[idx];
#pragma unroll
  for (int ex = 0; ex < NEXP; ++ex) {
    const unsigned long long m = __ballot(e == ex);
    if (m && lane == 0) atomicAdd(&hdr[ex], __popcll(m));
  }
}

// -------- build permutation + inverse map, wave-aggregated cursors ---------
// hdr[16..23] = cursors
__global__ __launch_bounds__(256) void moe_build(
    const int* __restrict__ meta_e, int* __restrict__ hdr,
    int* __restrict__ tok, int* __restrict__ inv) {
  const int idx = blockIdx.x * 256 + threadIdx.x;  // over NPOS entries
  const int lane = threadIdx.x & 63;
  const int token = idx >> 1;
  const int e = meta_e[idx];
  int pos = 0;
#pragma unroll
  for (int ex = 0; ex < NEXP; ++ex) {
    const unsigned long long m = __ballot(e == ex);
    if (m) {
      const int leader = (int)__ffsll((long long)m) - 1;
      int base = 0;
      if (lane == leader) base = atomicAdd(&hdr[16 + ex], __popcll(m));
      base = __shfl(base, leader);
      if (e == ex) {
        const int2 co = cnt_off(hdr, ex);
        pos = co.y + base + (int)__popcll(m & ((1ull << lane) - 1ull));
      }
    }
  }
  tok[pos] = token;
  inv[idx] = pos;
}

// ---------------- gather x rows into bf16, expert-grouped ------------------
__global__ __launch_bounds__(256) void moe_gather(
    const float* __restrict__ x, const int* __restrict__ tok,
    unsigned short* __restrict__ Xg) {
  const int pos = blockIdx.x;
  const int t = tok[pos];
  const float4 v = ((const float4*)(x + (size_t)t * DIM))[threadIdx.x];
  ushort4 o = make_ushort4(f2bf(v.x), f2bf(v.y), f2bf(v.z), f2bf(v.w));
  ((ushort4*)(Xg + (size_t)pos * DIM))[threadIdx.x] = o;
}

// ---------- fused fp32 [E][R][C] -> bf16 [E][C][R] transpose (all 3) -------
// 64x64 tiles: float4 loads, uint4 (8x bf16, 16B) stores.
__global__ __launch_bounds__(256) void moe_transpose_all(
    const float* __restrict__ W1, const float* __restrict__ W3,
    const float* __restrict__ W2,
    unsigned short* __restrict__ W1t, unsigned short* __restrict__ W3t,
    unsigned short* __restrict__ W2t) {
  __shared__ float tile[64][65];
  const int z = blockIdx.z;
  const int which = z >> 3, e = z & 7;
  const float* src; unsigned short* dst; int R, C;
  if (which == 0)      { src = W1; dst = W1t; R = DIM; C = HID; }
  else if (which == 1) { src = W3; dst = W3t; R = DIM; C = HID; }
  else                 { src = W2; dst = W2t; R = HID; C = DIM; }
  const int nbx = C / 64;
  const int bx = blockIdx.x % nbx, by = blockIdx.x / nbx;
  const float* ein = src + (size_t)e * R * C;
  unsigned short* eout = dst + (size_t)e * R * C;
  const int c0 = bx * 64, r0 = by * 64;
  const int lx = threadIdx.x & 15, ly = threadIdx.x >> 4;
#pragma unroll
  for (int it = 0; it < 4; ++it) {
    const int r = ly + it * 16;
    const float4 v = *(const float4*)&ein[(size_t)(r0 + r) * C + c0 + lx * 4];
    tile[r][lx * 4 + 0] = v.x;
    tile[r][lx * 4 + 1] = v.y;
    tile[r][lx * 4 + 2] = v.z;
    tile[r][lx * 4 + 3] = v.w;
  }
  __syncthreads();
  // write: each lane emits 8 consecutive r (16B) for one cc row; 2 rows/lane.
  const int r8 = (threadIdx.x & 7) * 8;
  const int ccb = threadIdx.x >> 3;       // [0,32)
#pragma unroll
  for (int it = 0; it < 2; ++it) {
    const int cc = ccb + it * 32;
    unsigned int w0 = (unsigned int)f2bf(tile[r8 + 0][cc]) | ((unsigned int)f2bf(tile[r8 + 1][cc]) << 16);
    unsigned int w1 = (unsigned int)f2bf(tile[r8 + 2][cc]) | ((unsigned int)f2bf(tile[r8 + 3][cc]) << 16);
    unsigned int w2 = (unsigned int)f2bf(tile[r8 + 4][cc]) | ((unsigned int)f2bf(tile[r8 + 5][cc]) << 16);
    unsigned int w3 = (unsigned int)f2bf(tile[r8 + 6][cc]) | ((unsigned int)f2bf(tile[r8 + 7][cc]) << 16);
    uint4 o = make_uint4(w0, w1, w2, w3);
    *(uint4*)&eout[(size_t)(c0 + cc) * R + r0 + r8] = o;
  }
}

// XOR-swizzled LDS layout (BK=32 sub-tile, 64 B rows):
//   logical (row, kg) [kg = 16B k-group 0..3] stored at row*64B + (kg ^ ((row>>1)&3))*16B.
//   Staged via global_load_lds lane->base+lane*16: lane holds (row=lane>>2, slot=lane&3),
//   so it must FETCH global kg = (lane&3) ^ ((lane>>3)&3).
//   Fragment read slot for quarter q=(lane>>4): q ^ ((lane>>1)&3).
// 2-phase prefetch pipeline (T3 minimum): double-buffered BK=32 sub-tiles;
// issue next sub-tile's global_load_lds BEFORE computing current; ONE
// __syncthreads (vmcnt(0)+lgkmcnt(0) drain) per sub-tile -> load latency
// overlaps ds_read+MFMA instead of being exposed at issue.

// ---------------- GEMM1: Hbuf = silu(Xg@W1) * (Xg@W3), grouped -------------
// 128x64 tile (dual-B = effective 128x128). Grid-stride persistent blocks,
// baseline-linear decode (round-3 lesson: XCD remap hurt A-panel L2 sharing).
__global__ __launch_bounds__(256) void moe_gemm1(
    const unsigned short* __restrict__ Xg,
    const unsigned short* __restrict__ W1t,
    const unsigned short* __restrict__ W3t,
    unsigned short* __restrict__ Hbuf,
    const int* __restrict__ hdr) {
  const int e = blockIdx.y;
  const int NT = HID / 64;   // 24
  const int TROW = 16;       // row-tile grid stride
  const int tileN = blockIdx.x % NT;
  const int tr0 = blockIdx.x / NT;
  const int2 co = cnt_off(hdr, e);
  const int cnt = co.x;
  const int off = co.y;
  const int n0 = tileN * 64;

  __shared__ unsigned short As[2][128 * 32];   // 2x8 KB
  __shared__ unsigned short B1s[2][64 * 32];   // 2x4 KB
  __shared__ unsigned short B3s[2][64 * 32];   // 2x4 KB

  const int lane = threadIdx.x & 63;
  const int wave = threadIdx.x >> 6;
  const int wm = wave >> 1, wn = wave & 1;
  const int rsub = lane >> 2;                               // staging row in 16-row chunk
  const int ksw  = (((lane & 3) ^ ((lane >> 3) & 3))) * 8;  // swizzled k-short offset
  const int kf   = (((lane >> 4) ^ ((lane >> 1) & 3))) * 8; // fragment k-short offset

  const unsigned short* B1base = W1t + ((size_t)e * HID + n0) * DIM;
  const unsigned short* B3base = W3t + ((size_t)e * HID + n0) * DIM;
  const unsigned short* Abase;

  floatx4 zero = {0.f, 0.f, 0.f, 0.f};
  floatx4 acc_h[4][2], acc_g[4][2];

  auto stage = [&](int b, int kk) {
#pragma unroll
    for (int t2 = 0; t2 < 2; ++t2) {
      const int c = wave * 2 + t2;
      async_cp16(&As[b][c * 512], Abase + (size_t)(c * 16 + rsub) * DIM + kk + ksw);
    }
    async_cp16(&B1s[b][wave * 512], B1base + (size_t)(wave * 16 + rsub) * DIM + kk + ksw);
    async_cp16(&B3s[b][wave * 512], B3base + (size_t)(wave * 16 + rsub) * DIM + kk + ksw);
  };
  auto compute = [&](int b) {
    bf16x8 a[4], b1[2], b3[2];
#pragma unroll
    for (int i = 0; i < 4; ++i)
      a[i] = *(const bf16x8*)&As[b][(wm * 64 + i * 16 + (lane & 15)) * 32 + kf];
#pragma unroll
    for (int j = 0; j < 2; ++j) {
      b1[j] = *(const bf16x8*)&B1s[b][(wn * 32 + j * 16 + (lane & 15)) * 32 + kf];
      b3[j] = *(const bf16x8*)&B3s[b][(wn * 32 + j * 16 + (lane & 15)) * 32 + kf];
    }
#pragma unroll
    for (int i = 0; i < 4; ++i)
#pragma unroll
      for (int j = 0; j < 2; ++j) {
        acc_h[i][j] = __builtin_amdgcn_mfma_f32_16x16x32_bf16(a[i], b1[j], acc_h[i][j], 0, 0, 0);
        acc_g[i][j] = __builtin_amdgcn_mfma_f32_16x16x32_bf16(a[i], b3[j], acc_g[i][j], 0, 0, 0);
      }
  };

  for (int tileRow = tr0; tileRow * 128 < cnt; tileRow += TROW) {
    Abase = Xg + ((size_t)off + (size_t)tileRow * 128) * DIM;
#pragma unroll
    for (int i = 0; i < 4; ++i)
#pragma unroll
      for (int j = 0; j < 2; ++j) { acc_h[i][j] = zero; acc_g[i][j] = zero; }

    // 32 sub-tiles of BK=32 over K=1024, 2-phase prefetch
    stage(0, 0);
    __syncthreads();
#pragma unroll 1
    for (int kt = 0; kt < 15; ++kt) {
      stage(1, (2 * kt + 1) * 32); compute(0); __syncthreads();
      stage(0, (2 * kt + 2) * 32); compute(1); __syncthreads();
    }
    stage(1, 31 * 32); compute(0); __syncthreads();
    compute(1);

    // epilogue: silu(h)*g -> bf16, guarded against tile overrun into next expert
    const int r0 = (lane >> 4) * 4;
    const int cc = lane & 15;
#pragma unroll
    for (int i = 0; i < 4; ++i)
#pragma unroll
      for (int r = 0; r < 4; ++r) {
        const int lrow = tileRow * 128 + wm * 64 + i * 16 + r0 + r;
        if (lrow < cnt) {
          unsigned short* hrow = Hbuf + (size_t)(off + lrow) * HID + n0 + wn * 32 + cc;
#pragma unroll
          for (int j = 0; j < 2; ++j) {
            const float h = acc_h[i][j][r];
            const float g = acc_g[i][j][r];
            const float s = h / (1.f + expf(-h));
            hrow[j * 16] = f2bf(s * g);
          }
        }
      }
    // next row-tile's prologue stages buf0; last reads here were buf1 and
    // buf0's last read preceded a barrier all waves crossed -> no hazard.
  }
}

// ---------------- GEMM2: Y[pos] = Hbuf @ W2 (bf16 rows, no atomics) --------
// 128x128 tile, 2-phase prefetch, grid-stride persistent blocks.
__global__ __launch_bounds__(256) void moe_gemm2(
    const unsigned short* __restrict__ Hbuf,
    const unsigned short* __restrict__ W2t,
    const int* __restrict__ hdr,
    unsigned short* __restrict__ Y) {
  const int e = blockIdx.y;
  const int NT = DIM / 128;  // 8
  const int TROW = 16;
  const int tileN = blockIdx.x % NT;
  const int tr0 = blockIdx.x / NT;
  const int2 co = cnt_off(hdr, e);
  const int cnt = co.x;
  const int off = co.y;
  const int n0 = tileN * 128;

  __shared__ unsigned short As[2][128 * 32];   // 2x8 KB
  __shared__ unsigned short Bs[2][128 * 32];   // 2x8 KB

  const int lane = threadIdx.x & 63;
  const int wave = threadIdx.x >> 6;
  const int wm = wave >> 1, wn = wave & 1;
  const int rsub = lane >> 2;
  const int ksw  = (((lane & 3) ^ ((lane >> 3) & 3))) * 8;
  const int kf   = (((lane >> 4) ^ ((lane >> 1) & 3))) * 8;

  const unsigned short* Bbase = W2t + ((size_t)e * DIM + n0) * HID;
  const unsigned short* Abase;

  floatx4 zero = {0.f, 0.f, 0.f, 0.f};
  floatx4 acc[4][4];

  auto stage = [&](int b, int kk) {
#pragma unroll
    for (int t2 = 0; t2 < 2; ++t2) {
      const int c = wave * 2 + t2;
      async_cp16(&As[b][c * 512], Abase + (size_t)(c * 16 + rsub) * HID + kk + ksw);
      async_cp16(&Bs[b][c * 512], Bbase + (size_t)(c * 16 + rsub) * HID + kk + ksw);
    }
  };
  auto compute = [&](int bb) {
    bf16x8 a[4], b[4];
#pragma unroll
    for (int i = 0; i < 4; ++i)
      a[i] = *(const bf16x8*)&As[bb][(wm * 64 + i * 16 + (lane & 15)) * 32 + kf];
#pragma unroll
    for (int j = 0; j < 4; ++j)
      b[j] = *(const bf16x8*)&Bs[bb][(wn * 64 + j * 16 + (lane & 15)) * 32 + kf];
#pragma unroll
    for (int i = 0; i < 4; ++i)
#pragma unroll
      for (int j = 0; j < 4; ++j)
        acc[i][j] = __builtin_amdgcn_mfma_f32_16x16x32_bf16(a[i], b[j], acc[i][j], 0, 0, 0);
  };

  for (int tileRow = tr0; tileRow * 128 < cnt; tileRow += TROW) {
    Abase = Hbuf + ((size_t)off + (size_t)tileRow * 128) * HID;
#pragma unroll
    for (int i = 0; i < 4; ++i)
#pragma unroll
      for (int j = 0; j < 4; ++j) acc[i][j] = zero;

    // 48 sub-tiles of BK=32 over K=1536, 2-phase prefetch
    stage(0, 0);
    __syncthreads();
#pragma unroll 1
    for (int kt = 0; kt < 23; ++kt) {
      stage(1, (2 * kt + 1) * 32); compute(0); __syncthreads();
      stage(0, (2 * kt + 2) * 32); compute(1); __syncthreads();
    }
    stage(1, 47 * 32); compute(0); __syncthreads();
    compute(1);

    const int r0 = (lane >> 4) * 4;
    const int cc = lane & 15;
#pragma unroll
    for (int i = 0; i < 4; ++i)
#pragma unroll
      for (int r = 0; r < 4; ++r) {
        const int lrow = tileRow * 128 + wm * 64 + i * 16 + r0 + r;
        if (lrow < cnt) {
          unsigned short* yrow = Y + (size_t)(off + lrow) * DIM + n0 + wn * 64 + cc;
#pragma unroll
          for (int j = 0; j < 4; ++j)
            yrow[j * 16] = f2bf(acc[i][j][r]);
        }
      }
  }
}

// ---------------- combine: out[t] = w0*Y[p0] + w1*Y[p1] --------------------
__global__ __launch_bounds__(256) void moe_combine(
    const unsigned short* __restrict__ Y, const int* __restrict__ inv,
    const float* __restrict__ meta_w, float* __restrict__ out) {
  const int t = blockIdx.x;
  const int p0 = inv[t * 2 + 0], p1 = inv[t * 2 + 1];
  const float w0 = meta_w[t * 2 + 0], w1 = meta_w[t * 2 + 1];
  const ushort4 a = ((const ushort4*)(Y + (size_t)p0 * DIM))[threadIdx.x];
  const ushort4 b = ((const ushort4*)(Y + (size_t)p1 * DIM))[threadIdx.x];
  float4 o;
  o.x = w0 * bf2f(a.x) + w1 * bf2f(b.x);
  o.y = w0 * bf2f(a.y) + w1 * bf2f(b.y);
  o.z = w0 * bf2f(a.z) + w1 * bf2f(b.z);
  o.w = w0 * bf2f(a.w) + w1 * bf2f(b.w);
  ((float4*)(out + (size_t)t * DIM))[threadIdx.x] = o;
}

// ---------------------------------------------------------------------------
extern "C" void kernel_launch(void* const* d_in, const int* in_sizes, int n_in,
                              void* d_out, int out_size, void* d_ws, size_t ws_size,
                              hipStream_t stream) {
  const float* x  = (const float*)d_in[0];
  const float* Wr = (const float*)d_in[1];
  const float* W1 = (const float*)d_in[2];
  const float* W2 = (const float*)d_in[3];
  const float* W3 = (const float*)d_in[4];
  float* out = (float*)d_out;

  char* p = (char*)d_ws;
  auto carve = [&](size_t bytes) { char* r = p; p += (bytes + 255) & ~(size_t)255; return r; };

  int*            hdr    = (int*)carve(256);
  int*            meta_e = (int*)carve((size_t)NTOK * 2 * sizeof(int));
  float*          meta_w = (float*)carve((size_t)NTOK * 2 * sizeof(float));
  int*            tok    = (int*)carve((size_t)NPOS * sizeof(int));
  int*            inv    = (int*)carve((size_t)NTOK * 2 * sizeof(int));
  unsigned short* Xg     = (unsigned short*)carve((size_t)(NPOS + PADR) * DIM * 2);
  unsigned short* Hbuf   = (unsigned short*)carve((size_t)(NPOS + PADR) * HID * 2);
  unsigned short* W1t    = (unsigned short*)carve((size_t)NEXP * HID * DIM * 2);
  unsigned short* W3t    = (unsigned short*)carve((size_t)NEXP * HID * DIM * 2);
  unsigned short* W2t    = (unsigned short*)carve((size_t)NEXP * DIM * HID * 2);
  unsigned short* Y      = Xg;  // Xg is dead after gemm1; reuse as Y buffer

  hipMemsetAsync(hdr, 0, 256, stream);

  moe_router<<<NTOK / 4, 256, 0, stream>>>(x, Wr, meta_e, meta_w);
  moe_hist<<<NPOS / 256, 256, 0, stream>>>(meta_e, hdr);
  moe_build<<<NPOS / 256, 256, 0, stream>>>(meta_e, hdr, tok, inv);
  moe_gather<<<NPOS, 256, 0, stream>>>(x, tok, Xg);

  // W1 [E][1024][1536] -> W1t [E][1536][1024]; same for W3; W2 -> [E][1024][1536]
  moe_transpose_all<<<dim3(384, 1, 24), dim3(256), 0, stream>>>(W1, W3, W2, W1t, W3t, W2t);

  // persistent blocks: 16 row-tiles/expert, grid-stride over extra rows
  moe_gemm1<<<dim3(16 * (HID / 64), NEXP), 256, 0, stream>>>(Xg, W1t, W3t, Hbuf, hdr);
  moe_gemm2<<<dim3(16 * (DIM / 128), NEXP), 256, 0, stream>>>(Hbuf, W2t, hdr, Y);
  moe_combine<<<NTOK, 256, 0, stream>>>(Y, inv, meta_w, out);
}

// Round 6
// 592.509 us; speedup vs baseline: 1.0507x; 1.0507x over previous
//
#include <hip/hip_runtime.h>
#include <hip/hip_bf16.h>
#include <math.h>

#define DIM   1024
#define NEXP  8
#define HID   1536
#define NTOK  8192
#define NPOS  16384   // NTOK * TOP_K
#define PADR  128     // padding rows for tile overrun reads

typedef __attribute__((ext_vector_type(8))) short bf16x8;
typedef __attribute__((ext_vector_type(4))) float floatx4;

__device__ __forceinline__ unsigned short f2bf(float f) {
  unsigned int u = __float_as_uint(f);
  u += 0x7FFFu + ((u >> 16) & 1u);   // round-to-nearest-even
  return (unsigned short)(u >> 16);
}

__device__ __forceinline__ float bf2f(unsigned short h) {
  return __uint_as_float((unsigned int)h << 16);
}

__device__ __forceinline__ void async_cp16(void* lds, const void* g) {
  __builtin_amdgcn_global_load_lds(
      (const __attribute__((address_space(1))) unsigned int*)g,
      (__attribute__((address_space(3))) unsigned int*)lds, 16, 0, 0);
}

// count + exclusive-prefix offset for expert e, from hdr[0..7]
__device__ __forceinline__ int2 cnt_off(const int* __restrict__ hdr, int e) {
  int s = 0, c = 0;
#pragma unroll
  for (int i = 0; i < NEXP; ++i) {
    const int v = hdr[i];
    if (i < e) s += v;
    if (i == e) c = v;
  }
  return make_int2(c, s);
}

// ---------------- router: logits, top-2, softmax (no atomics) --------------
__global__ __launch_bounds__(256) void moe_router(
    const float* __restrict__ x, const float* __restrict__ Wr,
    int* __restrict__ meta_e, float* __restrict__ meta_w) {
  const int wave = threadIdx.x >> 6, lane = threadIdx.x & 63;
  const int token = blockIdx.x * 4 + wave;
  const float* xr = x + (size_t)token * DIM;
  float acc[NEXP];
#pragma unroll
  for (int e = 0; e < NEXP; ++e) acc[e] = 0.f;
  for (int i = lane; i < DIM; i += 64) {
    const float xv = xr[i];
    const float* wr = Wr + (size_t)i * NEXP;
#pragma unroll
    for (int e = 0; e < NEXP; ++e) acc[e] += xv * wr[e];
  }
#pragma unroll
  for (int off = 32; off > 0; off >>= 1) {
#pragma unroll
    for (int e = 0; e < NEXP; ++e) acc[e] += __shfl_down(acc[e], off);
  }
  if (lane == 0) {
    int i0 = 0; float v0 = acc[0];
#pragma unroll
    for (int e = 1; e < NEXP; ++e) if (acc[e] > v0) { v0 = acc[e]; i0 = e; }
    int i1 = -1; float v1 = -3.4e38f;
#pragma unroll
    for (int e = 0; e < NEXP; ++e) if (e != i0 && acc[e] > v1) { v1 = acc[e]; i1 = e; }
    const float w0 = 1.f / (1.f + expf(v1 - v0));  // stable softmax over top-2
    meta_e[token * 2 + 0] = i0;
    meta_e[token * 2 + 1] = i1;
    meta_w[token * 2 + 0] = w0;
    meta_w[token * 2 + 1] = 1.f - w0;
  }
}

// ------------- histogram: wave-aggregated counts into hdr[0..7] ------------
__global__ __launch_bounds__(256) void moe_hist(
    const int* __restrict__ meta_e, int* __restrict__ hdr) {
  const int idx = blockIdx.x * 256 + threadIdx.x;  // over NPOS entries
  const int lane = threadIdx.x & 63;
  const int e = meta_e[idx];
#pragma unroll
  for (int ex = 0; ex < NEXP; ++ex) {
    const unsigned long long m = __ballot(e == ex);
    if (m && lane == 0) atomicAdd(&hdr[ex], __popcll(m));
  }
}

// -------- build permutation + inverse map, wave-aggregated cursors ---------
// hdr[16..23] = cursors
__global__ __launch_bounds__(256) void moe_build(
    const int* __restrict__ meta_e, int* __restrict__ hdr,
    int* __restrict__ tok, int* __restrict__ inv) {
  const int idx = blockIdx.x * 256 + threadIdx.x;  // over NPOS entries
  const int lane = threadIdx.x & 63;
  const int token = idx >> 1;
  const int e = meta_e[idx];
  int pos = 0;
#pragma unroll
  for (int ex = 0; ex < NEXP; ++ex) {
    const unsigned long long m = __ballot(e == ex);
    if (m) {
      const int leader = (int)__ffsll((long long)m) - 1;
      int base = 0;
      if (lane == leader) base = atomicAdd(&hdr[16 + ex], __popcll(m));
      base = __shfl(base, leader);
      if (e == ex) {
        const int2 co = cnt_off(hdr, ex);
        pos = co.y + base + (int)__popcll(m & ((1ull << lane) - 1ull));
      }
    }
  }
  tok[pos] = token;
  inv[idx] = pos;
}

// ---------------- gather x rows into bf16, expert-grouped ------------------
__global__ __launch_bounds__(256) void moe_gather(
    const float* __restrict__ x, const int* __restrict__ tok,
    unsigned short* __restrict__ Xg) {
  const int pos = blockIdx.x;
  const int t = tok[pos];
  const float4 v = ((const float4*)(x + (size_t)t * DIM))[threadIdx.x];
  ushort4 o = make_ushort4(f2bf(v.x), f2bf(v.y), f2bf(v.z), f2bf(v.w));
  ((ushort4*)(Xg + (size_t)pos * DIM))[threadIdx.x] = o;
}

// ---------- fused fp32 [E][R][C] -> bf16 [E][C][R] transpose (all 3) -------
// 64x64 tiles: float4 loads, uint4 (8x bf16, 16B) stores.
__global__ __launch_bounds__(256) void moe_transpose_all(
    const float* __restrict__ W1, const float* __restrict__ W3,
    const float* __restrict__ W2,
    unsigned short* __restrict__ W1t, unsigned short* __restrict__ W3t,
    unsigned short* __restrict__ W2t) {
  __shared__ float tile[64][65];
  const int z = blockIdx.z;
  const int which = z >> 3, e = z & 7;
  const float* src; unsigned short* dst; int R, C;
  if (which == 0)      { src = W1; dst = W1t; R = DIM; C = HID; }
  else if (which == 1) { src = W3; dst = W3t; R = DIM; C = HID; }
  else                 { src = W2; dst = W2t; R = HID; C = DIM; }
  const int nbx = C / 64;
  const int bx = blockIdx.x % nbx, by = blockIdx.x / nbx;
  const float* ein = src + (size_t)e * R * C;
  unsigned short* eout = dst + (size_t)e * R * C;
  const int c0 = bx * 64, r0 = by * 64;
  const int lx = threadIdx.x & 15, ly = threadIdx.x >> 4;
#pragma unroll
  for (int it = 0; it < 4; ++it) {
    const int r = ly + it * 16;
    const float4 v = *(const float4*)&ein[(size_t)(r0 + r) * C + c0 + lx * 4];
    tile[r][lx * 4 + 0] = v.x;
    tile[r][lx * 4 + 1] = v.y;
    tile[r][lx * 4 + 2] = v.z;
    tile[r][lx * 4 + 3] = v.w;
  }
  __syncthreads();
  // write: each lane emits 8 consecutive r (16B) for one cc row; 2 rows/lane.
  const int r8 = (threadIdx.x & 7) * 8;
  const int ccb = threadIdx.x >> 3;       // [0,32)
#pragma unroll
  for (int it = 0; it < 2; ++it) {
    const int cc = ccb + it * 32;
    unsigned int w0 = (unsigned int)f2bf(tile[r8 + 0][cc]) | ((unsigned int)f2bf(tile[r8 + 1][cc]) << 16);
    unsigned int w1 = (unsigned int)f2bf(tile[r8 + 2][cc]) | ((unsigned int)f2bf(tile[r8 + 3][cc]) << 16);
    unsigned int w2 = (unsigned int)f2bf(tile[r8 + 4][cc]) | ((unsigned int)f2bf(tile[r8 + 5][cc]) << 16);
    unsigned int w3 = (unsigned int)f2bf(tile[r8 + 6][cc]) | ((unsigned int)f2bf(tile[r8 + 7][cc]) << 16);
    uint4 o = make_uint4(w0, w1, w2, w3);
    *(uint4*)&eout[(size_t)(c0 + cc) * R + r0 + r8] = o;
  }
}

// XOR-swizzled LDS layout (BK=32 sub-tile, 64 B rows):
//   logical (row, kg) [kg = 16B k-group 0..3] stored at row*64B + (kg ^ ((row>>1)&3))*16B.
//   Staged via global_load_lds lane->base+lane*16: lane holds (row=lane>>2, slot=lane&3),
//   so it must FETCH global kg = (lane&3) ^ ((lane>>3)&3).
//   Fragment read slot for quarter q=(lane>>4): q ^ ((lane>>1)&3).
// Cross-iteration prefetch (lean): per BK=32 sub-tile, STAGE(next buf) then
// COMPUTE(cur) then ONE __syncthreads. Same barrier count as round-4, but
// each load has a full compute phase in flight before the barrier drains it.
// Round-5 lesson: implementation must be register-lean — pointers hoisted,
// macros not lambdas, no grid-stride state (VGPR 124 -> occupancy 21% killed it).

// ---------------- GEMM1: Hbuf = silu(Xg@W1) * (Xg@W3), grouped -------------
// 128x64 tile, dual-B fused. Worst-case grid, early return (proven).
__global__ __launch_bounds__(256) void moe_gemm1(
    const unsigned short* __restrict__ Xg,
    const unsigned short* __restrict__ W1t,
    const unsigned short* __restrict__ W3t,
    unsigned short* __restrict__ Hbuf,
    const int* __restrict__ hdr) {
  const int e = blockIdx.y;
  const int NT = HID / 64;  // 24
  const int tileRow = blockIdx.x / NT;
  const int tileN = blockIdx.x % NT;
  const int2 co = cnt_off(hdr, e);
  const int cnt = co.x;
  if (tileRow * 128 >= cnt) return;
  const int off = co.y;
  const size_t tileM = (size_t)off + (size_t)tileRow * 128;
  const int n0 = tileN * 64;

  __shared__ unsigned short As[2][128 * 32];   // 2x8 KB
  __shared__ unsigned short B1s[2][64 * 32];   // 2x4 KB
  __shared__ unsigned short B3s[2][64 * 32];   // 2x4 KB

  const int lane = threadIdx.x & 63;
  const int wave = threadIdx.x >> 6;
  const int wm = wave >> 1, wn = wave & 1;
  const int rsub = lane >> 2;                               // staging row in 16-row chunk
  const int ksw  = (((lane & 3) ^ ((lane >> 3) & 3))) * 8;  // swizzled k-short offset
  const int kf   = (((lane >> 4) ^ ((lane >> 1) & 3))) * 8; // fragment k-short offset

  // staging source pointers, hoisted (loop adds only a literal k offset)
  const unsigned short* pA0 = Xg + (tileM + (size_t)((wave * 2 + 0) * 16 + rsub)) * DIM + ksw;
  const unsigned short* pA1 = Xg + (tileM + (size_t)((wave * 2 + 1) * 16 + rsub)) * DIM + ksw;
  const unsigned short* pB1 = W1t + ((size_t)e * HID + n0 + wave * 16 + rsub) * DIM + ksw;
  const unsigned short* pB3 = W3t + ((size_t)e * HID + n0 + wave * 16 + rsub) * DIM + ksw;

  floatx4 zero = {0.f, 0.f, 0.f, 0.f};
  floatx4 acc_h[4][2], acc_g[4][2];
#pragma unroll
  for (int i = 0; i < 4; ++i)
#pragma unroll
    for (int j = 0; j < 2; ++j) { acc_h[i][j] = zero; acc_g[i][j] = zero; }

#define G1_STAGE(b, KK) \
    async_cp16(&As[b][(wave * 2 + 0) * 512], pA0 + (KK)); \
    async_cp16(&As[b][(wave * 2 + 1) * 512], pA1 + (KK)); \
    async_cp16(&B1s[b][wave * 512], pB1 + (KK)); \
    async_cp16(&B3s[b][wave * 512], pB3 + (KK));

#define G1_COMP(b) { \
    bf16x8 a[4], b1[2], b3[2]; \
    _Pragma("unroll") \
    for (int i = 0; i < 4; ++i) \
      a[i] = *(const bf16x8*)&As[b][(wm * 64 + i * 16 + (lane & 15)) * 32 + kf]; \
    _Pragma("unroll") \
    for (int j = 0; j < 2; ++j) { \
      b1[j] = *(const bf16x8*)&B1s[b][(wn * 32 + j * 16 + (lane & 15)) * 32 + kf]; \
      b3[j] = *(const bf16x8*)&B3s[b][(wn * 32 + j * 16 + (lane & 15)) * 32 + kf]; \
    } \
    _Pragma("unroll") \
    for (int i = 0; i < 4; ++i) \
      _Pragma("unroll") \
      for (int j = 0; j < 2; ++j) { \
        acc_h[i][j] = __builtin_amdgcn_mfma_f32_16x16x32_bf16(a[i], b1[j], acc_h[i][j], 0, 0, 0); \
        acc_g[i][j] = __builtin_amdgcn_mfma_f32_16x16x32_bf16(a[i], b3[j], acc_g[i][j], 0, 0, 0); \
      } \
  }

  // 32 sub-tiles of BK=32 over K=1024
  G1_STAGE(0, 0)
  __syncthreads();
  int kk = 0;
#pragma unroll 1
  for (int kt = 0; kt < 15; ++kt) {
    G1_STAGE(1, kk + 32) G1_COMP(0) __syncthreads();
    kk += 64;
    G1_STAGE(0, kk)      G1_COMP(1) __syncthreads();
  }
  G1_STAGE(1, kk + 32) G1_COMP(0) __syncthreads();
  G1_COMP(1)
#undef G1_STAGE
#undef G1_COMP

  // epilogue: silu(h)*g -> bf16, guarded against tile overrun into next expert
  const int r0 = (lane >> 4) * 4;
  const int cc = lane & 15;
#pragma unroll
  for (int i = 0; i < 4; ++i)
#pragma unroll
    for (int r = 0; r < 4; ++r) {
      const int lrow = tileRow * 128 + wm * 64 + i * 16 + r0 + r;
      if (lrow < cnt) {
        unsigned short* hrow = Hbuf + (size_t)(off + lrow) * HID + n0 + wn * 32 + cc;
#pragma unroll
        for (int j = 0; j < 2; ++j) {
          const float h = acc_h[i][j][r];
          const float g = acc_g[i][j][r];
          const float s = h / (1.f + expf(-h));
          hrow[j * 16] = f2bf(s * g);
        }
      }
    }
}

// ---------------- GEMM2: Y[pos] = Hbuf @ W2 (bf16 rows, no atomics) --------
// 128x128 tile. Worst-case grid, early return. Same lean prefetch pipeline.
__global__ __launch_bounds__(256) void moe_gemm2(
    const unsigned short* __restrict__ Hbuf,
    const unsigned short* __restrict__ W2t,
    const int* __restrict__ hdr,
    unsigned short* __restrict__ Y) {
  const int e = blockIdx.y;
  const int NT = DIM / 128;  // 8
  const int tileRow = blockIdx.x / NT;
  const int tileN = blockIdx.x % NT;
  const int2 co = cnt_off(hdr, e);
  const int cnt = co.x;
  if (tileRow * 128 >= cnt) return;
  const int off = co.y;
  const size_t tileM = (size_t)off + (size_t)tileRow * 128;
  const int n0 = tileN * 128;

  __shared__ unsigned short As[2][128 * 32];   // 2x8 KB
  __shared__ unsigned short Bs[2][128 * 32];   // 2x8 KB

  const int lane = threadIdx.x & 63;
  const int wave = threadIdx.x >> 6;
  const int wm = wave >> 1, wn = wave & 1;
  const int rsub = lane >> 2;
  const int ksw  = (((lane & 3) ^ ((lane >> 3) & 3))) * 8;
  const int kf   = (((lane >> 4) ^ ((lane >> 1) & 3))) * 8;

  const unsigned short* qA0 = Hbuf + (tileM + (size_t)((wave * 2 + 0) * 16 + rsub)) * HID + ksw;
  const unsigned short* qA1 = Hbuf + (tileM + (size_t)((wave * 2 + 1) * 16 + rsub)) * HID + ksw;
  const unsigned short* qB0 = W2t + ((size_t)e * DIM + n0 + (wave * 2 + 0) * 16 + rsub) * HID + ksw;
  const unsigned short* qB1 = W2t + ((size_t)e * DIM + n0 + (wave * 2 + 1) * 16 + rsub) * HID + ksw;

  floatx4 zero = {0.f, 0.f, 0.f, 0.f};
  floatx4 acc[4][4];
#pragma unroll
  for (int i = 0; i < 4; ++i)
#pragma unroll
    for (int j = 0; j < 4; ++j) acc[i][j] = zero;

#define G2_STAGE(b, KK) \
    async_cp16(&As[b][(wave * 2 + 0) * 512], qA0 + (KK)); \
    async_cp16(&As[b][(wave * 2 + 1) * 512], qA1 + (KK)); \
    async_cp16(&Bs[b][(wave * 2 + 0) * 512], qB0 + (KK)); \
    async_cp16(&Bs[b][(wave * 2 + 1) * 512], qB1 + (KK));

#define G2_COMP(bb) { \
    bf16x8 a[4], b[4]; \
    _Pragma("unroll") \
    for (int i = 0; i < 4; ++i) \
      a[i] = *(const bf16x8*)&As[bb][(wm * 64 + i * 16 + (lane & 15)) * 32 + kf]; \
    _Pragma("unroll") \
    for (int j = 0; j < 4; ++j) \
      b[j] = *(const bf16x8*)&Bs[bb][(wn * 64 + j * 16 + (lane & 15)) * 32 + kf]; \
    _Pragma("unroll") \
    for (int i = 0; i < 4; ++i) \
      _Pragma("unroll") \
      for (int j = 0; j < 4; ++j) \
        acc[i][j] = __builtin_amdgcn_mfma_f32_16x16x32_bf16(a[i], b[j], acc[i][j], 0, 0, 0); \
  }

  // 48 sub-tiles of BK=32 over K=1536
  G2_STAGE(0, 0)
  __syncthreads();
  int kk = 0;
#pragma unroll 1
  for (int kt = 0; kt < 23; ++kt) {
    G2_STAGE(1, kk + 32) G2_COMP(0) __syncthreads();
    kk += 64;
    G2_STAGE(0, kk)      G2_COMP(1) __syncthreads();
  }
  G2_STAGE(1, kk + 32) G2_COMP(0) __syncthreads();
  G2_COMP(1)
#undef G2_STAGE
#undef G2_COMP

  const int r0 = (lane >> 4) * 4;
  const int cc = lane & 15;
#pragma unroll
  for (int i = 0; i < 4; ++i)
#pragma unroll
    for (int r = 0; r < 4; ++r) {
      const int lrow = tileRow * 128 + wm * 64 + i * 16 + r0 + r;
      if (lrow < cnt) {
        unsigned short* yrow = Y + (size_t)(off + lrow) * DIM + n0 + wn * 64 + cc;
#pragma unroll
        for (int j = 0; j < 4; ++j)
          yrow[j * 16] = f2bf(acc[i][j][r]);
      }
    }
}

// ---------------- combine: out[t] = w0*Y[p0] + w1*Y[p1] --------------------
__global__ __launch_bounds__(256) void moe_combine(
    const unsigned short* __restrict__ Y, const int* __restrict__ inv,
    const float* __restrict__ meta_w, float* __restrict__ out) {
  const int t = blockIdx.x;
  const int p0 = inv[t * 2 + 0], p1 = inv[t * 2 + 1];
  const float w0 = meta_w[t * 2 + 0], w1 = meta_w[t * 2 + 1];
  const ushort4 a = ((const ushort4*)(Y + (size_t)p0 * DIM))[threadIdx.x];
  const ushort4 b = ((const ushort4*)(Y + (size_t)p1 * DIM))[threadIdx.x];
  float4 o;
  o.x = w0 * bf2f(a.x) + w1 * bf2f(b.x);
  o.y = w0 * bf2f(a.y) + w1 * bf2f(b.y);
  o.z = w0 * bf2f(a.z) + w1 * bf2f(b.z);
  o.w = w0 * bf2f(a.w) + w1 * bf2f(b.w);
  ((float4*)(out + (size_t)t * DIM))[threadIdx.x] = o;
}

// ---------------------------------------------------------------------------
extern "C" void kernel_launch(void* const* d_in, const int* in_sizes, int n_in,
                              void* d_out, int out_size, void* d_ws, size_t ws_size,
                              hipStream_t stream) {
  const float* x  = (const float*)d_in[0];
  const float* Wr = (const float*)d_in[1];
  const float* W1 = (const float*)d_in[2];
  const float* W2 = (const float*)d_in[3];
  const float* W3 = (const float*)d_in[4];
  float* out = (float*)d_out;

  char* p = (char*)d_ws;
  auto carve = [&](size_t bytes) { char* r = p; p += (bytes + 255) & ~(size_t)255; return r; };

  int*            hdr    = (int*)carve(256);
  int*            meta_e = (int*)carve((size_t)NTOK * 2 * sizeof(int));
  float*          meta_w = (float*)carve((size_t)NTOK * 2 * sizeof(float));
  int*            tok    = (int*)carve((size_t)NPOS * sizeof(int));
  int*            inv    = (int*)carve((size_t)NTOK * 2 * sizeof(int));
  unsigned short* Xg     = (unsigned short*)carve((size_t)(NPOS + PADR) * DIM * 2);
  unsigned short* Hbuf   = (unsigned short*)carve((size_t)(NPOS + PADR) * HID * 2);
  unsigned short* W1t    = (unsigned short*)carve((size_t)NEXP * HID * DIM * 2);
  unsigned short* W3t    = (unsigned short*)carve((size_t)NEXP * HID * DIM * 2);
  unsigned short* W2t    = (unsigned short*)carve((size_t)NEXP * DIM * HID * 2);
  unsigned short* Y      = Xg;  // Xg is dead after gemm1; reuse as Y buffer

  hipMemsetAsync(hdr, 0, 256, stream);

  moe_router<<<NTOK / 4, 256, 0, stream>>>(x, Wr, meta_e, meta_w);
  moe_hist<<<NPOS / 256, 256, 0, stream>>>(meta_e, hdr);
  moe_build<<<NPOS / 256, 256, 0, stream>>>(meta_e, hdr, tok, inv);
  moe_gather<<<NPOS, 256, 0, stream>>>(x, tok, Xg);

  // W1 [E][1024][1536] -> W1t [E][1536][1024]; same for W3; W2 -> [E][1024][1536]
  moe_transpose_all<<<dim3(384, 1, 24), dim3(256), 0, stream>>>(W1, W3, W2, W1t, W3t, W2t);

  // worst case one expert holds all 8192 tokens -> 64 row tiles
  moe_gemm1<<<dim3(64 * (HID / 64), NEXP), 256, 0, stream>>>(Xg, W1t, W3t, Hbuf, hdr);
  moe_gemm2<<<dim3(64 * (DIM / 128), NEXP), 256, 0, stream>>>(Hbuf, W2t, hdr, Y);
  moe_combine<<<NTOK, 256, 0, stream>>>(Y, inv, meta_w, out);
}

// Round 7
// 579.416 us; speedup vs baseline: 1.0745x; 1.0226x over previous
//
#include <hip/hip_runtime.h>
#include <hip/hip_bf16.h>
#include <math.h>

#define DIM   1024
#define NEXP  8
#define HID   1536
#define NTOK  8192
#define NPOS  16384   // NTOK * TOP_K
#define PADR  128     // padding rows for tile overrun reads

typedef __attribute__((ext_vector_type(8))) short bf16x8;
typedef __attribute__((ext_vector_type(4))) float floatx4;

__device__ __forceinline__ unsigned short f2bf(float f) {
  unsigned int u = __float_as_uint(f);
  u += 0x7FFFu + ((u >> 16) & 1u);   // round-to-nearest-even
  return (unsigned short)(u >> 16);
}

__device__ __forceinline__ float bf2f(unsigned short h) {
  return __uint_as_float((unsigned int)h << 16);
}

__device__ __forceinline__ void async_cp16(void* lds, const void* g) {
  __builtin_amdgcn_global_load_lds(
      (const __attribute__((address_space(1))) unsigned int*)g,
      (__attribute__((address_space(3))) unsigned int*)lds, 16, 0, 0);
}

// count + exclusive-prefix offset for expert e, from hdr[0..7]
__device__ __forceinline__ int2 cnt_off(const int* __restrict__ hdr, int e) {
  int s = 0, c = 0;
#pragma unroll
  for (int i = 0; i < NEXP; ++i) {
    const int v = hdr[i];
    if (i < e) s += v;
    if (i == e) c = v;
  }
  return make_int2(c, s);
}

// compiler fence + raw-barrier helpers (counted vmcnt: NEVER vmcnt(0) in loop)
#define FENCE asm volatile("" ::: "memory")
#define WAIT_LGKM0_BAR do { asm volatile("s_waitcnt lgkmcnt(0)" ::: "memory"); \
    __builtin_amdgcn_s_barrier(); FENCE; } while (0)
#define WAIT_VM4_BAR   do { asm volatile("s_waitcnt vmcnt(4)" ::: "memory"); \
    __builtin_amdgcn_s_barrier(); FENCE; } while (0)
#define WAIT_VM0_BAR   do { asm volatile("s_waitcnt vmcnt(0)" ::: "memory"); \
    __builtin_amdgcn_s_barrier(); FENCE; } while (0)

// ---------------- router: logits, top-2, softmax (no atomics) --------------
__global__ __launch_bounds__(256) void moe_router(
    const float* __restrict__ x, const float* __restrict__ Wr,
    int* __restrict__ meta_e, float* __restrict__ meta_w) {
  const int wave = threadIdx.x >> 6, lane = threadIdx.x & 63;
  const int token = blockIdx.x * 4 + wave;
  const float* xr = x + (size_t)token * DIM;
  float acc[NEXP];
#pragma unroll
  for (int e = 0; e < NEXP; ++e) acc[e] = 0.f;
  for (int i = lane; i < DIM; i += 64) {
    const float xv = xr[i];
    const float* wr = Wr + (size_t)i * NEXP;
#pragma unroll
    for (int e = 0; e < NEXP; ++e) acc[e] += xv * wr[e];
  }
#pragma unroll
  for (int off = 32; off > 0; off >>= 1) {
#pragma unroll
    for (int e = 0; e < NEXP; ++e) acc[e] += __shfl_down(acc[e], off);
  }
  if (lane == 0) {
    int i0 = 0; float v0 = acc[0];
#pragma unroll
    for (int e = 1; e < NEXP; ++e) if (acc[e] > v0) { v0 = acc[e]; i0 = e; }
    int i1 = -1; float v1 = -3.4e38f;
#pragma unroll
    for (int e = 0; e < NEXP; ++e) if (e != i0 && acc[e] > v1) { v1 = acc[e]; i1 = e; }
    const float w0 = 1.f / (1.f + expf(v1 - v0));  // stable softmax over top-2
    meta_e[token * 2 + 0] = i0;
    meta_e[token * 2 + 1] = i1;
    meta_w[token * 2 + 0] = w0;
    meta_w[token * 2 + 1] = 1.f - w0;
  }
}

// ------------- histogram: wave-aggregated counts into hdr[0..7] ------------
__global__ __launch_bounds__(256) void moe_hist(
    const int* __restrict__ meta_e, int* __restrict__ hdr) {
  const int idx = blockIdx.x * 256 + threadIdx.x;  // over NPOS entries
  const int lane = threadIdx.x & 63;
  const int e = meta_e[idx];
#pragma unroll
  for (int ex = 0; ex < NEXP; ++ex) {
    const unsigned long long m = __ballot(e == ex);
    if (m && lane == 0) atomicAdd(&hdr[ex], __popcll(m));
  }
}

// -------- build permutation + inverse map, wave-aggregated cursors ---------
// hdr[16..23] = cursors
__global__ __launch_bounds__(256) void moe_build(
    const int* __restrict__ meta_e, int* __restrict__ hdr,
    int* __restrict__ tok, int* __restrict__ inv) {
  const int idx = blockIdx.x * 256 + threadIdx.x;  // over NPOS entries
  const int lane = threadIdx.x & 63;
  const int token = idx >> 1;
  const int e = meta_e[idx];
  int pos = 0;
#pragma unroll
  for (int ex = 0; ex < NEXP; ++ex) {
    const unsigned long long m = __ballot(e == ex);
    if (m) {
      const int leader = (int)__ffsll((long long)m) - 1;
      int base = 0;
      if (lane == leader) base = atomicAdd(&hdr[16 + ex], __popcll(m));
      base = __shfl(base, leader);
      if (e == ex) {
        const int2 co = cnt_off(hdr, ex);
        pos = co.y + base + (int)__popcll(m & ((1ull << lane) - 1ull));
      }
    }
  }
  tok[pos] = token;
  inv[idx] = pos;
}

// ---------------- gather x rows into bf16, expert-grouped ------------------
__global__ __launch_bounds__(256) void moe_gather(
    const float* __restrict__ x, const int* __restrict__ tok,
    unsigned short* __restrict__ Xg) {
  const int pos = blockIdx.x;
  const int t = tok[pos];
  const float4 v = ((const float4*)(x + (size_t)t * DIM))[threadIdx.x];
  ushort4 o = make_ushort4(f2bf(v.x), f2bf(v.y), f2bf(v.z), f2bf(v.w));
  ((ushort4*)(Xg + (size_t)pos * DIM))[threadIdx.x] = o;
}

// ---------- fused fp32 [E][R][C] -> bf16 [E][C][R] transpose (all 3) -------
// 64x64 tiles: float4 loads, uint4 (8x bf16, 16B) stores.
__global__ __launch_bounds__(256) void moe_transpose_all(
    const float* __restrict__ W1, const float* __restrict__ W3,
    const float* __restrict__ W2,
    unsigned short* __restrict__ W1t, unsigned short* __restrict__ W3t,
    unsigned short* __restrict__ W2t) {
  __shared__ float tile[64][65];
  const int z = blockIdx.z;
  const int which = z >> 3, e = z & 7;
  const float* src; unsigned short* dst; int R, C;
  if (which == 0)      { src = W1; dst = W1t; R = DIM; C = HID; }
  else if (which == 1) { src = W3; dst = W3t; R = DIM; C = HID; }
  else                 { src = W2; dst = W2t; R = HID; C = DIM; }
  const int nbx = C / 64;
  const int bx = blockIdx.x % nbx, by = blockIdx.x / nbx;
  const float* ein = src + (size_t)e * R * C;
  unsigned short* eout = dst + (size_t)e * R * C;
  const int c0 = bx * 64, r0 = by * 64;
  const int lx = threadIdx.x & 15, ly = threadIdx.x >> 4;
#pragma unroll
  for (int it = 0; it < 4; ++it) {
    const int r = ly + it * 16;
    const float4 v = *(const float4*)&ein[(size_t)(r0 + r) * C + c0 + lx * 4];
    tile[r][lx * 4 + 0] = v.x;
    tile[r][lx * 4 + 1] = v.y;
    tile[r][lx * 4 + 2] = v.z;
    tile[r][lx * 4 + 3] = v.w;
  }
  __syncthreads();
  // write: each lane emits 8 consecutive r (16B) for one cc row; 2 rows/lane.
  const int r8 = (threadIdx.x & 7) * 8;
  const int ccb = threadIdx.x >> 3;       // [0,32)
#pragma unroll
  for (int it = 0; it < 2; ++it) {
    const int cc = ccb + it * 32;
    unsigned int w0 = (unsigned int)f2bf(tile[r8 + 0][cc]) | ((unsigned int)f2bf(tile[r8 + 1][cc]) << 16);
    unsigned int w1 = (unsigned int)f2bf(tile[r8 + 2][cc]) | ((unsigned int)f2bf(tile[r8 + 3][cc]) << 16);
    unsigned int w2 = (unsigned int)f2bf(tile[r8 + 4][cc]) | ((unsigned int)f2bf(tile[r8 + 5][cc]) << 16);
    unsigned int w3 = (unsigned int)f2bf(tile[r8 + 6][cc]) | ((unsigned int)f2bf(tile[r8 + 7][cc]) << 16);
    uint4 o = make_uint4(w0, w1, w2, w3);
    *(uint4*)&eout[(size_t)(c0 + cc) * R + r0 + r8] = o;
  }
}

// XOR-swizzled LDS layout (BK=32 tile, 64 B rows):
//   logical (row, kg) [kg = 16B k-group 0..3] stored at row*64B + (kg ^ ((row>>1)&3))*16B.
//   Staged via global_load_lds lane->base+lane*16: lane fetches global
//   kg = (lane&3) ^ ((lane>>3)&3). Fragment read slot for quarter q=(lane>>4):
//   q ^ ((lane>>1)&3).
// Counted-vmcnt pipeline (T4; round-6 lesson: __syncthreads' vmcnt(0) drain
// makes HIP-level prefetch useless — raw s_barrier + counted waits required):
//   prologue: STAGE(t0) STAGE(t1); vmcnt(4); bar.
//   per tile: ds_read frags; lgkmcnt(0); bar  (all waves done reading buf)
//             STAGE(t+2 into same buf); MFMA (overlaps loads)
//             vmcnt(4); bar  (tile t+1 ready; this tile's loads in flight)
//   tails drain vmcnt(0). Ledger: 4 loads/tile/wave, in-order completion,
//   8 outstanding at each wait -> vmcnt(4) releases exactly the older tile.

// ---------------- GEMM1: Hbuf = silu(Xg@W1) * (Xg@W3), grouped -------------
// 128x64 tile, dual-B fused. Worst-case grid, early return (proven r4 skel).
__global__ __launch_bounds__(256) void moe_gemm1(
    const unsigned short* __restrict__ Xg,
    const unsigned short* __restrict__ W1t,
    const unsigned short* __restrict__ W3t,
    unsigned short* __restrict__ Hbuf,
    const int* __restrict__ hdr) {
  const int e = blockIdx.y;
  const int NT = HID / 64;  // 24
  const int tileRow = blockIdx.x / NT;
  const int tileN = blockIdx.x % NT;
  const int2 co = cnt_off(hdr, e);
  const int cnt = co.x;
  if (tileRow * 128 >= cnt) return;
  const int off = co.y;
  const size_t tileM = (size_t)off + (size_t)tileRow * 128;
  const int n0 = tileN * 64;

  __shared__ unsigned short As[2][128 * 32];   // 2x8 KB
  __shared__ unsigned short B1s[2][64 * 32];   // 2x4 KB
  __shared__ unsigned short B3s[2][64 * 32];   // 2x4 KB

  const int lane = threadIdx.x & 63;
  const int wave = threadIdx.x >> 6;
  const int wm = wave >> 1, wn = wave & 1;
  const int rsub = lane >> 2;                               // staging row in 16-row chunk
  const int ksw  = (((lane & 3) ^ ((lane >> 3) & 3))) * 8;  // swizzled k-short offset
  const int kf   = (((lane >> 4) ^ ((lane >> 1) & 3))) * 8; // fragment k-short offset

  // staging source pointers, hoisted (loop adds only a k offset)
  const unsigned short* pA0 = Xg + (tileM + (size_t)((wave * 2 + 0) * 16 + rsub)) * DIM + ksw;
  const unsigned short* pA1 = Xg + (tileM + (size_t)((wave * 2 + 1) * 16 + rsub)) * DIM + ksw;
  const unsigned short* pB1 = W1t + ((size_t)e * HID + n0 + wave * 16 + rsub) * DIM + ksw;
  const unsigned short* pB3 = W3t + ((size_t)e * HID + n0 + wave * 16 + rsub) * DIM + ksw;

  floatx4 zero = {0.f, 0.f, 0.f, 0.f};
  floatx4 acc_h[4][2], acc_g[4][2];
#pragma unroll
  for (int i = 0; i < 4; ++i)
#pragma unroll
    for (int j = 0; j < 2; ++j) { acc_h[i][j] = zero; acc_g[i][j] = zero; }

#define G1_STAGE(B, KK) \
    async_cp16(&As[B][(wave * 2 + 0) * 512], pA0 + (KK)); \
    async_cp16(&As[B][(wave * 2 + 1) * 512], pA1 + (KK)); \
    async_cp16(&B1s[B][wave * 512], pB1 + (KK)); \
    async_cp16(&B3s[B][wave * 512], pB3 + (KK));

#define G1_READ(B) \
    _Pragma("unroll") \
    for (int i = 0; i < 4; ++i) \
      a[i] = *(const bf16x8*)&As[B][(wm * 64 + i * 16 + (lane & 15)) * 32 + kf]; \
    _Pragma("unroll") \
    for (int j = 0; j < 2; ++j) { \
      b1[j] = *(const bf16x8*)&B1s[B][(wn * 32 + j * 16 + (lane & 15)) * 32 + kf]; \
      b3[j] = *(const bf16x8*)&B3s[B][(wn * 32 + j * 16 + (lane & 15)) * 32 + kf]; \
    }

#define G1_MFMA \
    _Pragma("unroll") \
    for (int i = 0; i < 4; ++i) \
      _Pragma("unroll") \
      for (int j = 0; j < 2; ++j) { \
        acc_h[i][j] = __builtin_amdgcn_mfma_f32_16x16x32_bf16(a[i], b1[j], acc_h[i][j], 0, 0, 0); \
        acc_g[i][j] = __builtin_amdgcn_mfma_f32_16x16x32_bf16(a[i], b3[j], acc_g[i][j], 0, 0, 0); \
      }

  // 32 tiles of BK=32 over K=1024, depth-2 counted-vmcnt pipeline
  G1_STAGE(0, 0)
  G1_STAGE(1, 32)
  WAIT_VM4_BAR;
  int kk = 64;
#pragma unroll 1
  for (int kt = 0; kt < 15; ++kt) {
    {
      bf16x8 a[4], b1[2], b3[2];
      G1_READ(0)
      WAIT_LGKM0_BAR;
      G1_STAGE(0, kk)
      G1_MFMA
    }
    WAIT_VM4_BAR;
    {
      bf16x8 a[4], b1[2], b3[2];
      G1_READ(1)
      WAIT_LGKM0_BAR;
      G1_STAGE(1, kk + 32)
      G1_MFMA
    }
    WAIT_VM4_BAR;
    kk += 64;
  }
  // tails: tile 30 (buf0; nothing overwrites it), tile 31 (buf1)
  {
    bf16x8 a[4], b1[2], b3[2];
    G1_READ(0)
    G1_MFMA
  }
  WAIT_VM0_BAR;
  {
    bf16x8 a[4], b1[2], b3[2];
    G1_READ(1)
    G1_MFMA
  }
#undef G1_STAGE
#undef G1_READ
#undef G1_MFMA

  // epilogue: silu(h)*g -> bf16, guarded against tile overrun into next expert
  const int r0 = (lane >> 4) * 4;
  const int cc = lane & 15;
#pragma unroll
  for (int i = 0; i < 4; ++i)
#pragma unroll
    for (int r = 0; r < 4; ++r) {
      const int lrow = tileRow * 128 + wm * 64 + i * 16 + r0 + r;
      if (lrow < cnt) {
        unsigned short* hrow = Hbuf + (size_t)(off + lrow) * HID + n0 + wn * 32 + cc;
#pragma unroll
        for (int j = 0; j < 2; ++j) {
          const float h = acc_h[i][j][r];
          const float g = acc_g[i][j][r];
          const float s = h / (1.f + expf(-h));
          hrow[j * 16] = f2bf(s * g);
        }
      }
    }
}

// ---------------- GEMM2: Y[pos] = Hbuf @ W2 (bf16 rows, no atomics) --------
// 128x128 tile. Worst-case grid, early return. Same counted-vmcnt pipeline.
__global__ __launch_bounds__(256) void moe_gemm2(
    const unsigned short* __restrict__ Hbuf,
    const unsigned short* __restrict__ W2t,
    const int* __restrict__ hdr,
    unsigned short* __restrict__ Y) {
  const int e = blockIdx.y;
  const int NT = DIM / 128;  // 8
  const int tileRow = blockIdx.x / NT;
  const int tileN = blockIdx.x % NT;
  const int2 co = cnt_off(hdr, e);
  const int cnt = co.x;
  if (tileRow * 128 >= cnt) return;
  const int off = co.y;
  const size_t tileM = (size_t)off + (size_t)tileRow * 128;
  const int n0 = tileN * 128;

  __shared__ unsigned short As[2][128 * 32];   // 2x8 KB
  __shared__ unsigned short Bs[2][128 * 32];   // 2x8 KB

  const int lane = threadIdx.x & 63;
  const int wave = threadIdx.x >> 6;
  const int wm = wave >> 1, wn = wave & 1;
  const int rsub = lane >> 2;
  const int ksw  = (((lane & 3) ^ ((lane >> 3) & 3))) * 8;
  const int kf   = (((lane >> 4) ^ ((lane >> 1) & 3))) * 8;

  const unsigned short* qA0 = Hbuf + (tileM + (size_t)((wave * 2 + 0) * 16 + rsub)) * HID + ksw;
  const unsigned short* qA1 = Hbuf + (tileM + (size_t)((wave * 2 + 1) * 16 + rsub)) * HID + ksw;
  const unsigned short* qB0 = W2t + ((size_t)e * DIM + n0 + (wave * 2 + 0) * 16 + rsub) * HID + ksw;
  const unsigned short* qB1 = W2t + ((size_t)e * DIM + n0 + (wave * 2 + 1) * 16 + rsub) * HID + ksw;

  floatx4 zero = {0.f, 0.f, 0.f, 0.f};
  floatx4 acc[4][4];
#pragma unroll
  for (int i = 0; i < 4; ++i)
#pragma unroll
    for (int j = 0; j < 4; ++j) acc[i][j] = zero;

#define G2_STAGE(B, KK) \
    async_cp16(&As[B][(wave * 2 + 0) * 512], qA0 + (KK)); \
    async_cp16(&As[B][(wave * 2 + 1) * 512], qA1 + (KK)); \
    async_cp16(&Bs[B][(wave * 2 + 0) * 512], qB0 + (KK)); \
    async_cp16(&Bs[B][(wave * 2 + 1) * 512], qB1 + (KK));

#define G2_READ(B) \
    _Pragma("unroll") \
    for (int i = 0; i < 4; ++i) \
      a[i] = *(const bf16x8*)&As[B][(wm * 64 + i * 16 + (lane & 15)) * 32 + kf]; \
    _Pragma("unroll") \
    for (int j = 0; j < 4; ++j) \
      b[j] = *(const bf16x8*)&Bs[B][(wn * 64 + j * 16 + (lane & 15)) * 32 + kf];

#define G2_MFMA \
    _Pragma("unroll") \
    for (int i = 0; i < 4; ++i) \
      _Pragma("unroll") \
      for (int j = 0; j < 4; ++j) \
        acc[i][j] = __builtin_amdgcn_mfma_f32_16x16x32_bf16(a[i], b[j], acc[i][j], 0, 0, 0);

  // 48 tiles of BK=32 over K=1536, depth-2 counted-vmcnt pipeline
  G2_STAGE(0, 0)
  G2_STAGE(1, 32)
  WAIT_VM4_BAR;
  int kk = 64;
#pragma unroll 1
  for (int kt = 0; kt < 23; ++kt) {
    {
      bf16x8 a[4], b[4];
      G2_READ(0)
      WAIT_LGKM0_BAR;
      G2_STAGE(0, kk)
      G2_MFMA
    }
    WAIT_VM4_BAR;
    {
      bf16x8 a[4], b[4];
      G2_READ(1)
      WAIT_LGKM0_BAR;
      G2_STAGE(1, kk + 32)
      G2_MFMA
    }
    WAIT_VM4_BAR;
    kk += 64;
  }
  // tails: tile 46 (buf0), tile 47 (buf1)
  {
    bf16x8 a[4], b[4];
    G2_READ(0)
    G2_MFMA
  }
  WAIT_VM0_BAR;
  {
    bf16x8 a[4], b[4];
    G2_READ(1)
    G2_MFMA
  }
#undef G2_STAGE
#undef G2_READ
#undef G2_MFMA

  const int r0 = (lane >> 4) * 4;
  const int cc = lane & 15;
#pragma unroll
  for (int i = 0; i < 4; ++i)
#pragma unroll
    for (int r = 0; r < 4; ++r) {
      const int lrow = tileRow * 128 + wm * 64 + i * 16 + r0 + r;
      if (lrow < cnt) {
        unsigned short* yrow = Y + (size_t)(off + lrow) * DIM + n0 + wn * 64 + cc;
#pragma unroll
        for (int j = 0; j < 4; ++j)
          yrow[j * 16] = f2bf(acc[i][j][r]);
      }
    }
}

// ---------------- combine: out[t] = w0*Y[p0] + w1*Y[p1] --------------------
__global__ __launch_bounds__(256) void moe_combine(
    const unsigned short* __restrict__ Y, const int* __restrict__ inv,
    const float* __restrict__ meta_w, float* __restrict__ out) {
  const int t = blockIdx.x;
  const int p0 = inv[t * 2 + 0], p1 = inv[t * 2 + 1];
  const float w0 = meta_w[t * 2 + 0], w1 = meta_w[t * 2 + 1];
  const ushort4 a = ((const ushort4*)(Y + (size_t)p0 * DIM))[threadIdx.x];
  const ushort4 b = ((const ushort4*)(Y + (size_t)p1 * DIM))[threadIdx.x];
  float4 o;
  o.x = w0 * bf2f(a.x) + w1 * bf2f(b.x);
  o.y = w0 * bf2f(a.y) + w1 * bf2f(b.y);
  o.z = w0 * bf2f(a.z) + w1 * bf2f(b.z);
  o.w = w0 * bf2f(a.w) + w1 * bf2f(b.w);
  ((float4*)(out + (size_t)t * DIM))[threadIdx.x] = o;
}

// ---------------------------------------------------------------------------
extern "C" void kernel_launch(void* const* d_in, const int* in_sizes, int n_in,
                              void* d_out, int out_size, void* d_ws, size_t ws_size,
                              hipStream_t stream) {
  const float* x  = (const float*)d_in[0];
  const float* Wr = (const float*)d_in[1];
  const float* W1 = (const float*)d_in[2];
  const float* W2 = (const float*)d_in[3];
  const float* W3 = (const float*)d_in[4];
  float* out = (float*)d_out;

  char* p = (char*)d_ws;
  auto carve = [&](size_t bytes) { char* r = p; p += (bytes + 255) & ~(size_t)255; return r; };

  int*            hdr    = (int*)carve(256);
  int*            meta_e = (int*)carve((size_t)NTOK * 2 * sizeof(int));
  float*          meta_w = (float*)carve((size_t)NTOK * 2 * sizeof(float));
  int*            tok    = (int*)carve((size_t)NPOS * sizeof(int));
  int*            inv    = (int*)carve((size_t)NTOK * 2 * sizeof(int));
  unsigned short* Xg     = (unsigned short*)carve((size_t)(NPOS + PADR) * DIM * 2);
  unsigned short* Hbuf   = (unsigned short*)carve((size_t)(NPOS + PADR) * HID * 2);
  unsigned short* W1t    = (unsigned short*)carve((size_t)NEXP * HID * DIM * 2);
  unsigned short* W3t    = (unsigned short*)carve((size_t)NEXP * HID * DIM * 2);
  unsigned short* W2t    = (unsigned short*)carve((size_t)NEXP * DIM * HID * 2);
  unsigned short* Y      = Xg;  // Xg is dead after gemm1; reuse as Y buffer

  hipMemsetAsync(hdr, 0, 256, stream);

  moe_router<<<NTOK / 4, 256, 0, stream>>>(x, Wr, meta_e, meta_w);
  moe_hist<<<NPOS / 256, 256, 0, stream>>>(meta_e, hdr);
  moe_build<<<NPOS / 256, 256, 0, stream>>>(meta_e, hdr, tok, inv);
  moe_gather<<<NPOS, 256, 0, stream>>>(x, tok, Xg);

  // W1 [E][1024][1536] -> W1t [E][1536][1024]; same for W3; W2 -> [E][1024][1536]
  moe_transpose_all<<<dim3(384, 1, 24), dim3(256), 0, stream>>>(W1, W3, W2, W1t, W3t, W2t);

  // worst case one expert holds all 8192 tokens -> 64 row tiles
  moe_gemm1<<<dim3(64 * (HID / 64), NEXP), 256, 0, stream>>>(Xg, W1t, W3t, Hbuf, hdr);
  moe_gemm2<<<dim3(64 * (DIM / 128), NEXP), 256, 0, stream>>>(Hbuf, W2t, hdr, Y);
  moe_combine<<<NTOK, 256, 0, stream>>>(Y, inv, meta_w, out);
}

// Round 8
// 519.144 us; speedup vs baseline: 1.1992x; 1.1161x over previous
//
#include <hip/hip_runtime.h>
#include <hip/hip_bf16.h>
#include <math.h>

#define DIM   1024
#define NEXP  8
#define HID   1536
#define NTOK  8192
#define NPOS  16384   // NTOK * TOP_K
#define PADR  128     // padding rows for tile overrun reads

typedef __attribute__((ext_vector_type(8))) short bf16x8;
typedef __attribute__((ext_vector_type(4))) float floatx4;

__device__ __forceinline__ unsigned short f2bf(float f) {
  unsigned int u = __float_as_uint(f);
  u += 0x7FFFu + ((u >> 16) & 1u);   // round-to-nearest-even
  return (unsigned short)(u >> 16);
}

__device__ __forceinline__ float bf2f(unsigned short h) {
  return __uint_as_float((unsigned int)h << 16);
}

__device__ __forceinline__ void async_cp16(void* lds, const void* g) {
  __builtin_amdgcn_global_load_lds(
      (const __attribute__((address_space(1))) unsigned int*)g,
      (__attribute__((address_space(3))) unsigned int*)lds, 16, 0, 0);
}

// count + exclusive-prefix offset for expert e, from hdr[0..7]
__device__ __forceinline__ int2 cnt_off(const int* __restrict__ hdr, int e) {
  int s = 0, c = 0;
#pragma unroll
  for (int i = 0; i < NEXP; ++i) {
    const int v = hdr[i];
    if (i < e) s += v;
    if (i == e) c = v;
  }
  return make_int2(c, s);
}

// ---- fused: router (blocks 0..2047) | weight transpose (blocks 2048..11263)
// Router: 1 wave per token, top-2 softmax, meta writes + LDS-aggregated hist.
// Transpose: fp32 [E][R][C] -> bf16 [E][C][R], 64x64 tiles, independent work
// fused via grid partition to kill two dispatch gaps in the serialized chain.
__global__ __launch_bounds__(256) void moe_router_transpose(
    const float* __restrict__ x, const float* __restrict__ Wr,
    int* __restrict__ meta_e, float* __restrict__ meta_w,
    int* __restrict__ hdr,
    const float* __restrict__ W1, const float* __restrict__ W3,
    const float* __restrict__ W2,
    unsigned short* __restrict__ W1t, unsigned short* __restrict__ W3t,
    unsigned short* __restrict__ W2t) {
  __shared__ float tile[64][65];     // transpose path
  __shared__ int hcnt[8];            // router path

  if (blockIdx.x < (NTOK / 4)) {
    // ---------------- router + hist ----------------
    if (threadIdx.x < 8) hcnt[threadIdx.x] = 0;
    __syncthreads();
    const int wave = threadIdx.x >> 6, lane = threadIdx.x & 63;
    const int token = blockIdx.x * 4 + wave;
    const float* xr = x + (size_t)token * DIM;
    float acc[NEXP];
#pragma unroll
    for (int e = 0; e < NEXP; ++e) acc[e] = 0.f;
    for (int i = lane; i < DIM; i += 64) {
      const float xv = xr[i];
      const float* wr = Wr + (size_t)i * NEXP;
#pragma unroll
      for (int e = 0; e < NEXP; ++e) acc[e] += xv * wr[e];
    }
#pragma unroll
    for (int off = 32; off > 0; off >>= 1) {
#pragma unroll
      for (int e = 0; e < NEXP; ++e) acc[e] += __shfl_down(acc[e], off);
    }
    if (lane == 0) {
      int i0 = 0; float v0 = acc[0];
#pragma unroll
      for (int e = 1; e < NEXP; ++e) if (acc[e] > v0) { v0 = acc[e]; i0 = e; }
      int i1 = -1; float v1 = -3.4e38f;
#pragma unroll
      for (int e = 0; e < NEXP; ++e) if (e != i0 && acc[e] > v1) { v1 = acc[e]; i1 = e; }
      const float w0 = 1.f / (1.f + expf(v1 - v0));  // stable softmax over top-2
      meta_e[token * 2 + 0] = i0;
      meta_e[token * 2 + 1] = i1;
      meta_w[token * 2 + 0] = w0;
      meta_w[token * 2 + 1] = 1.f - w0;
      atomicAdd(&hcnt[i0], 1);
      atomicAdd(&hcnt[i1], 1);
    }
    __syncthreads();
    if (threadIdx.x < 8) {
      const int c = hcnt[threadIdx.x];
      if (c) atomicAdd(&hdr[threadIdx.x], c);
    }
    return;
  }

  // ---------------- weight transpose ----------------
  const int id = blockIdx.x - (NTOK / 4);   // [0, 9216)
  const int tz = id / 384, tx = id % 384;
  const int which = tz >> 3, e = tz & 7;
  const float* src; unsigned short* dst; int R, C;
  if (which == 0)      { src = W1; dst = W1t; R = DIM; C = HID; }
  else if (which == 1) { src = W3; dst = W3t; R = DIM; C = HID; }
  else                 { src = W2; dst = W2t; R = HID; C = DIM; }
  const int nbx = C / 64;
  const int bx = tx % nbx, by = tx / nbx;
  const float* ein = src + (size_t)e * R * C;
  unsigned short* eout = dst + (size_t)e * R * C;
  const int c0 = bx * 64, r0 = by * 64;
  const int lx = threadIdx.x & 15, ly = threadIdx.x >> 4;
#pragma unroll
  for (int it = 0; it < 4; ++it) {
    const int r = ly + it * 16;
    const float4 v = *(const float4*)&ein[(size_t)(r0 + r) * C + c0 + lx * 4];
    tile[r][lx * 4 + 0] = v.x;
    tile[r][lx * 4 + 1] = v.y;
    tile[r][lx * 4 + 2] = v.z;
    tile[r][lx * 4 + 3] = v.w;
  }
  __syncthreads();
  // write: each lane emits 8 consecutive r (16B) for one cc row; 2 rows/lane.
  const int r8 = (threadIdx.x & 7) * 8;
  const int ccb = threadIdx.x >> 3;       // [0,32)
#pragma unroll
  for (int it = 0; it < 2; ++it) {
    const int cc = ccb + it * 32;
    unsigned int w0 = (unsigned int)f2bf(tile[r8 + 0][cc]) | ((unsigned int)f2bf(tile[r8 + 1][cc]) << 16);
    unsigned int w1 = (unsigned int)f2bf(tile[r8 + 2][cc]) | ((unsigned int)f2bf(tile[r8 + 3][cc]) << 16);
    unsigned int w2 = (unsigned int)f2bf(tile[r8 + 4][cc]) | ((unsigned int)f2bf(tile[r8 + 5][cc]) << 16);
    unsigned int w3 = (unsigned int)f2bf(tile[r8 + 6][cc]) | ((unsigned int)f2bf(tile[r8 + 7][cc]) << 16);
    uint4 o = make_uint4(w0, w1, w2, w3);
    *(uint4*)&eout[(size_t)(c0 + cc) * R + r0 + r8] = o;
  }
}

// -------- build permutation + per-position weight, wave-aggregated ---------
// hdr[16..23] = cursors. wpos[pos] feeds gemm2's fused combine epilogue.
__global__ __launch_bounds__(256) void moe_build(
    const int* __restrict__ meta_e, const float* __restrict__ meta_w,
    int* __restrict__ hdr, int* __restrict__ tok, float* __restrict__ wpos) {
  const int idx = blockIdx.x * 256 + threadIdx.x;  // over NPOS entries
  const int lane = threadIdx.x & 63;
  const int token = idx >> 1;
  const int e = meta_e[idx];
  int pos = 0;
#pragma unroll
  for (int ex = 0; ex < NEXP; ++ex) {
    const unsigned long long m = __ballot(e == ex);
    if (m) {
      const int leader = (int)__ffsll((long long)m) - 1;
      int base = 0;
      if (lane == leader) base = atomicAdd(&hdr[16 + ex], __popcll(m));
      base = __shfl(base, leader);
      if (e == ex) {
        const int2 co = cnt_off(hdr, ex);
        pos = co.y + base + (int)__popcll(m & ((1ull << lane) - 1ull));
      }
    }
  }
  tok[pos] = token;
  wpos[pos] = meta_w[idx];
}

// ---------------- gather x rows into bf16, expert-grouped ------------------
__global__ __launch_bounds__(256) void moe_gather(
    const float* __restrict__ x, const int* __restrict__ tok,
    unsigned short* __restrict__ Xg) {
  const int pos = blockIdx.x;
  const int t = tok[pos];
  const float4 v = ((const float4*)(x + (size_t)t * DIM))[threadIdx.x];
  ushort4 o = make_ushort4(f2bf(v.x), f2bf(v.y), f2bf(v.z), f2bf(v.w));
  ((ushort4*)(Xg + (size_t)pos * DIM))[threadIdx.x] = o;
}

// XOR-swizzled LDS layout (BK=32 sub-tile, 64 B rows):
//   logical (row, kg) [kg = 16B k-group 0..3] stored at row*64B + (kg ^ ((row>>1)&3))*16B.
//   Staged via global_load_lds lane->base+lane*16: lane fetches global
//   kg = (lane&3) ^ ((lane>>3)&3). Fragment read slot for quarter q=(lane>>4):
//   q ^ ((lane>>1)&3).
// BK=64 = two 32-k sub-tiles staged before ONE barrier pair (r4 structure).
// r5-r7 lesson: intra-block pipelining (2-phase, counted vmcnt) LOSES here —
// inter-block overlap (4-5 blocks/CU) already hides the drain; extra barriers
// only impede it. Keep the proven stage-all -> drain-all shape.

// ---------------- GEMM1: Hbuf = silu(Xg@W1) * (Xg@W3), grouped -------------
// 128x64 tile (dual-B = effective 128x128), BK=64. Worst-case grid, early ret.
__global__ __launch_bounds__(256) void moe_gemm1(
    const unsigned short* __restrict__ Xg,
    const unsigned short* __restrict__ W1t,
    const unsigned short* __restrict__ W3t,
    unsigned short* __restrict__ Hbuf,
    const int* __restrict__ hdr) {
  const int e = blockIdx.y;
  const int NT = HID / 64;  // 24
  const int tileRow = blockIdx.x / NT;
  const int tileN = blockIdx.x % NT;
  const int2 co = cnt_off(hdr, e);
  const int cnt = co.x;
  if (tileRow * 128 >= cnt) return;
  const int off = co.y;
  const size_t tileM = (size_t)off + (size_t)tileRow * 128;
  const int n0 = tileN * 64;

  __shared__ unsigned short As[2][128 * 32];   // 16 KB
  __shared__ unsigned short B1s[2][64 * 32];   // 8 KB
  __shared__ unsigned short B3s[2][64 * 32];   // 8 KB

  const int lane = threadIdx.x & 63;
  const int wave = threadIdx.x >> 6;
  const int wm = wave >> 1, wn = wave & 1;
  const int rsub = lane >> 2;                               // staging row in 16-row chunk
  const int ksw  = (((lane & 3) ^ ((lane >> 3) & 3))) * 8;  // swizzled k-short offset
  const int kf   = (((lane >> 4) ^ ((lane >> 1) & 3))) * 8; // fragment k-short offset

  const unsigned short* Abase = Xg + tileM * DIM;
  const unsigned short* B1base = W1t + ((size_t)e * HID + n0) * DIM;
  const unsigned short* B3base = W3t + ((size_t)e * HID + n0) * DIM;

  floatx4 zero = {0.f, 0.f, 0.f, 0.f};
  floatx4 acc_h[4][2], acc_g[4][2];
#pragma unroll
  for (int i = 0; i < 4; ++i)
#pragma unroll
    for (int j = 0; j < 2; ++j) { acc_h[i][j] = zero; acc_g[i][j] = zero; }

  for (int k0 = 0; k0 < DIM; k0 += 64) {
#pragma unroll
    for (int h = 0; h < 2; ++h) {
      const int kk = k0 + h * 32;
      // A: 8 chunks of 16 rows; chunks wave*2, wave*2+1
#pragma unroll
      for (int t = 0; t < 2; ++t) {
        const int c = wave * 2 + t;
        const int row = c * 16 + rsub;
        async_cp16(&As[h][c * 512], Abase + (size_t)row * DIM + kk + ksw);
      }
      // B1/B3: 4 chunks of 16 rows; chunk = wave
      const int row = wave * 16 + rsub;
      async_cp16(&B1s[h][wave * 512], B1base + (size_t)row * DIM + kk + ksw);
      async_cp16(&B3s[h][wave * 512], B3base + (size_t)row * DIM + kk + ksw);
    }
    __syncthreads();
#pragma unroll
    for (int h = 0; h < 2; ++h) {
      bf16x8 a[4], b1[2], b3[2];
#pragma unroll
      for (int i = 0; i < 4; ++i)
        a[i] = *(const bf16x8*)&As[h][(wm * 64 + i * 16 + (lane & 15)) * 32 + kf];
#pragma unroll
      for (int j = 0; j < 2; ++j) {
        b1[j] = *(const bf16x8*)&B1s[h][(wn * 32 + j * 16 + (lane & 15)) * 32 + kf];
        b3[j] = *(const bf16x8*)&B3s[h][(wn * 32 + j * 16 + (lane & 15)) * 32 + kf];
      }
#pragma unroll
      for (int i = 0; i < 4; ++i)
#pragma unroll
        for (int j = 0; j < 2; ++j) {
          acc_h[i][j] = __builtin_amdgcn_mfma_f32_16x16x32_bf16(a[i], b1[j], acc_h[i][j], 0, 0, 0);
          acc_g[i][j] = __builtin_amdgcn_mfma_f32_16x16x32_bf16(a[i], b3[j], acc_g[i][j], 0, 0, 0);
        }
    }
    __syncthreads();
  }

  // epilogue: silu(h)*g -> bf16, guarded against tile overrun into next expert
  const int r0 = (lane >> 4) * 4;
  const int cc = lane & 15;
#pragma unroll
  for (int i = 0; i < 4; ++i)
#pragma unroll
    for (int r = 0; r < 4; ++r) {
      const int lrow = tileRow * 128 + wm * 64 + i * 16 + r0 + r;
      if (lrow < cnt) {
        unsigned short* hrow = Hbuf + (size_t)(off + lrow) * HID + n0 + wn * 32 + cc;
#pragma unroll
        for (int j = 0; j < 2; ++j) {
          const float h = acc_h[i][j][r];
          const float g = acc_g[i][j][r];
          const float s = h / (1.f + expf(-h));
          hrow[j * 16] = f2bf(s * g);
        }
      }
    }
}

// ---------------- GEMM2 + fused combine: out += w * (Hbuf @ W2) ------------
// 128x128 tile, BK=64 (r4 structure). Epilogue atomically accumulates
// w*acc (fp32) into out[tok[pos]] — kills the combine kernel, the Y buffer,
// and its 67 MB round-trip. out zeroed by memset; each element gets exactly
// TOP_K=2 adds (tileN partitions columns, lrow guarded).
__global__ __launch_bounds__(256) void moe_gemm2(
    const unsigned short* __restrict__ Hbuf,
    const unsigned short* __restrict__ W2t,
    const int* __restrict__ hdr,
    const int* __restrict__ tok, const float* __restrict__ wpos,
    float* __restrict__ out) {
  const int e = blockIdx.y;
  const int NT = DIM / 128;  // 8
  const int tileRow = blockIdx.x / NT;
  const int tileN = blockIdx.x % NT;
  const int2 co = cnt_off(hdr, e);
  const int cnt = co.x;
  if (tileRow * 128 >= cnt) return;
  const int off = co.y;
  const size_t tileM = (size_t)off + (size_t)tileRow * 128;
  const int n0 = tileN * 128;

  __shared__ unsigned short As[2][128 * 32];   // 16 KB
  __shared__ unsigned short Bs[2][128 * 32];   // 16 KB

  const int lane = threadIdx.x & 63;
  const int wave = threadIdx.x >> 6;
  const int wm = wave >> 1, wn = wave & 1;
  const int rsub = lane >> 2;
  const int ksw  = (((lane & 3) ^ ((lane >> 3) & 3))) * 8;
  const int kf   = (((lane >> 4) ^ ((lane >> 1) & 3))) * 8;

  const unsigned short* Abase = Hbuf + tileM * HID;
  const unsigned short* Bbase = W2t + ((size_t)e * DIM + n0) * HID;

  floatx4 zero = {0.f, 0.f, 0.f, 0.f};
  floatx4 acc[4][4];
#pragma unroll
  for (int i = 0; i < 4; ++i)
#pragma unroll
    for (int j = 0; j < 4; ++j) acc[i][j] = zero;

  for (int k0 = 0; k0 < HID; k0 += 64) {
#pragma unroll
    for (int h = 0; h < 2; ++h) {
      const int kk = k0 + h * 32;
      // A: 8 chunks of 16 rows; chunks wave*2, wave*2+1
#pragma unroll
      for (int t = 0; t < 2; ++t) {
        const int c = wave * 2 + t;
        const int row = c * 16 + rsub;
        async_cp16(&As[h][c * 512], Abase + (size_t)row * HID + kk + ksw);
      }
      // B: 8 chunks of 16 rows; chunks wave*2, wave*2+1
#pragma unroll
      for (int t = 0; t < 2; ++t) {
        const int c = wave * 2 + t;
        const int row = c * 16 + rsub;
        async_cp16(&Bs[h][c * 512], Bbase + (size_t)row * HID + kk + ksw);
      }
    }
    __syncthreads();
#pragma unroll
    for (int h = 0; h < 2; ++h) {
      bf16x8 a[4], b[4];
#pragma unroll
      for (int i = 0; i < 4; ++i)
        a[i] = *(const bf16x8*)&As[h][(wm * 64 + i * 16 + (lane & 15)) * 32 + kf];
#pragma unroll
      for (int j = 0; j < 4; ++j)
        b[j] = *(const bf16x8*)&Bs[h][(wn * 64 + j * 16 + (lane & 15)) * 32 + kf];
#pragma unroll
      for (int i = 0; i < 4; ++i)
#pragma unroll
        for (int j = 0; j < 4; ++j)
          acc[i][j] = __builtin_amdgcn_mfma_f32_16x16x32_bf16(a[i], b[j], acc[i][j], 0, 0, 0);
    }
    __syncthreads();
  }

  const int r0 = (lane >> 4) * 4;
  const int cc = lane & 15;
#pragma unroll
  for (int i = 0; i < 4; ++i)
#pragma unroll
    for (int r = 0; r < 4; ++r) {
      const int lrow = tileRow * 128 + wm * 64 + i * 16 + r0 + r;
      if (lrow < cnt) {
        const int pos = off + lrow;
        const int t = tok[pos];          // broadcast across 16-lane group
        const float w = wpos[pos];
        float* orow = out + (size_t)t * DIM + n0 + wn * 64 + cc;
#pragma unroll
        for (int j = 0; j < 4; ++j)
          atomicAdd(&orow[j * 16], w * acc[i][j][r]);
      }
    }
}

// ---------------------------------------------------------------------------
extern "C" void kernel_launch(void* const* d_in, const int* in_sizes, int n_in,
                              void* d_out, int out_size, void* d_ws, size_t ws_size,
                              hipStream_t stream) {
  const float* x  = (const float*)d_in[0];
  const float* Wr = (const float*)d_in[1];
  const float* W1 = (const float*)d_in[2];
  const float* W2 = (const float*)d_in[3];
  const float* W3 = (const float*)d_in[4];
  float* out = (float*)d_out;

  char* p = (char*)d_ws;
  auto carve = [&](size_t bytes) { char* r = p; p += (bytes + 255) & ~(size_t)255; return r; };

  int*            hdr    = (int*)carve(256);
  int*            meta_e = (int*)carve((size_t)NTOK * 2 * sizeof(int));
  float*          meta_w = (float*)carve((size_t)NTOK * 2 * sizeof(float));
  int*            tok    = (int*)carve((size_t)NPOS * sizeof(int));
  float*          wpos   = (float*)carve((size_t)NPOS * sizeof(float));
  unsigned short* Xg     = (unsigned short*)carve((size_t)(NPOS + PADR) * DIM * 2);
  unsigned short* Hbuf   = (unsigned short*)carve((size_t)(NPOS + PADR) * HID * 2);
  unsigned short* W1t    = (unsigned short*)carve((size_t)NEXP * HID * DIM * 2);
  unsigned short* W3t    = (unsigned short*)carve((size_t)NEXP * HID * DIM * 2);
  unsigned short* W2t    = (unsigned short*)carve((size_t)NEXP * DIM * HID * 2);

  hipMemsetAsync(hdr, 0, 256, stream);
  hipMemsetAsync(out, 0, (size_t)NTOK * DIM * sizeof(float), stream);

  // fused router+hist (blocks 0..2047) | weight transpose (blocks 2048..11263)
  moe_router_transpose<<<NTOK / 4 + 24 * 384, 256, 0, stream>>>(
      x, Wr, meta_e, meta_w, hdr, W1, W3, W2, W1t, W3t, W2t);
  moe_build<<<NPOS / 256, 256, 0, stream>>>(meta_e, meta_w, hdr, tok, wpos);
  moe_gather<<<NPOS, 256, 0, stream>>>(x, tok, Xg);

  // worst case one expert holds all 8192 tokens -> 64 row tiles
  moe_gemm1<<<dim3(64 * (HID / 64), NEXP), 256, 0, stream>>>(Xg, W1t, W3t, Hbuf, hdr);
  moe_gemm2<<<dim3(64 * (DIM / 128), NEXP), 256, 0, stream>>>(Hbuf, W2t, hdr, tok, wpos, out);
}